// Round 1
// baseline (217.139 us; speedup 1.0000x reference)
//
#include <hip/hip_runtime.h>
#include <hip/hip_bf16.h>

#define B_ 8
#define L_ 2048
#define D_ 128
#define SCALE 0.08838834764831845f  // 1/sqrt(128)

typedef __attribute__((ext_vector_type(8))) short short8;  // 8 bf16 = 4 VGPR (MFMA A/B frag)
typedef __attribute__((ext_vector_type(4))) float f32x4;   // MFMA C/D frag

// Device-global scratch (zero-init irrelevant: fully rewritten every call).
__device__ float          g_lpart[2 * B_ * L_];        // rowsum partials [jhalf][b*L+i]
__device__ unsigned short g_vT[(size_t)B_ * D_ * L_];  // v^T as bf16: [b][d][i]

static __device__ __forceinline__ float4 ld4(const float* p) { return *(const float4*)p; }
static __device__ __forceinline__ short bf(float f) {
    union { __hip_bfloat16 h; short s; } u; u.h = __float2bfloat16(f); return u.s;
}
static __device__ __forceinline__ short8 pack8(float4 a, float4 b) {
    short8 r;
    r[0] = bf(a.x); r[1] = bf(a.y); r[2] = bf(a.z); r[3] = bf(a.w);
    r[4] = bf(b.x); r[5] = bf(b.y); r[6] = bf(b.z); r[7] = bf(b.w);
    return r;
}
static __device__ __forceinline__ f32x4 mfma16(short8 a, short8 b, f32x4 c) {
    return __builtin_amdgcn_mfma_f32_16x16x32_bf16(a, b, c, 0, 0, 0);
}

// K0: g_vT[b][d][i] = bf16(v[b][i][d]).  256 blocks x 256 thr, 64i x 128d tiles.
__global__ __launch_bounds__(256) void vT_kernel(const float* __restrict__ v) {
    __shared__ float t[64 * 132];  // [i][d], pitch 132
    const int tid = threadIdx.x;
    const int b = blockIdx.x >> 5, i0 = (blockIdx.x & 31) * 64;
    const float* vb = v + ((size_t)b * L_ + i0) * D_;
    #pragma unroll
    for (int c = 0; c < 8; ++c) {
        const int g = c * 256 + tid, row = g >> 5, c4 = (g & 31) * 4;
        *(float4*)(t + row * 132 + c4) = ld4(vb + (size_t)row * D_ + c4);
    }
    __syncthreads();
    #pragma unroll
    for (int c = 0; c < 4; ++c) {
        const int g = c * 256 + tid, d = g >> 3, i8 = (g & 7) * 8;
        short8 r;
        #pragma unroll
        for (int j = 0; j < 8; ++j) r[j] = bf(t[(i8 + j) * 132 + d]);
        *(short8*)(void*)(g_vT + ((size_t)b * D_ + d) * L_ + i0 + i8) = r;
    }
}

// K1: e = exp(score*SCALE) via MFMA, written UNNORMALIZED to attn (fp32);
// per-row partial sums -> g_lpart.  Grid: b x 32 i-tiles x 2 j-halves = 512.
// Wave w owns 16 i-rows (w*16); D-frag: row(i)=quad*4+reg, col(j)=lane&15.
__global__ __launch_bounds__(256) void score_exp_kernel(const float* __restrict__ q,
                                                        const float* __restrict__ v,
                                                        float* __restrict__ attn) {
    __shared__ short vs[64 * 136];  // bf16 v rows [j_local][k], pitch 136
    const int tid = threadIdx.x;
    const int b = blockIdx.x >> 6, it = (blockIdx.x >> 1) & 31, jh = blockIdx.x & 1;
    const int i0 = it * 64;
    const int w = tid >> 6, lid = tid & 63, n16 = lid & 15, quad = lid >> 4;

    // A-frags: A[m=lane&15][k=quad*8+j], m -> q row i0+w*16+n16, k chunks c*32
    short8 qa[4];
    const float* qrow = q + ((size_t)b * L_ + i0 + w * 16 + n16) * D_ + quad * 8;
    #pragma unroll
    for (int c = 0; c < 4; ++c) qa[c] = pack8(ld4(qrow + c * 32), ld4(qrow + c * 32 + 4));

    float racc[4] = {0.f, 0.f, 0.f, 0.f};
    const float* vbp = v + (size_t)b * L_ * D_;
    float* ab = attn + (size_t)b * L_ * L_;

    for (int jt = 0; jt < 16; ++jt) {
        const int jb = jh * 1024 + jt * 64;
        __syncthreads();
        #pragma unroll
        for (int c = 0; c < 4; ++c) {  // stage 64 v rows as bf16
            const int g = c * 256 + tid, row = g >> 4, col8 = (g & 15) * 8;
            const float* src = vbp + (size_t)(jb + row) * D_ + col8;
            *(short8*)(vs + row * 136 + col8) = pack8(ld4(src), ld4(src + 4));
        }
        __syncthreads();
        #pragma unroll
        for (int jc = 0; jc < 4; ++jc) {
            f32x4 d = {0.f, 0.f, 0.f, 0.f};
            #pragma unroll
            for (int c = 0; c < 4; ++c) {
                const short8 vf = *(const short8*)(vs + (jc * 16 + n16) * 136 + c * 32 + quad * 8);
                d = mfma16(qa[c], vf, d);
            }
            float* ap = ab + (size_t)(i0 + w * 16 + quad * 4) * L_ + jb + jc * 16 + n16;
            #pragma unroll
            for (int r = 0; r < 4; ++r) {
                const float e = __expf(d[r] * SCALE);
                racc[r] += e;
                ap[(size_t)r * L_] = e;
            }
        }
    }
    // sum over the 16 j-lanes (tid bits 0..3)
    #pragma unroll
    for (int m = 1; m <= 8; m <<= 1)
        #pragma unroll
        for (int r = 0; r < 4; ++r) racc[r] += __shfl_xor(racc[r], m, 64);
    if (n16 == 0) {
        const float4 o = make_float4(racc[0], racc[1], racc[2], racc[3]);
        *(float4*)(g_lpart + jh * (B_ * L_) + b * L_ + i0 + w * 16 + quad * 4) = o;
    }
}

// K2+K3 fused: for each attn tile read UNNORMALIZED e, scale by s=1/(l0+l1),
// write normalized attn back in place (block-exclusive j-columns -> no races),
// and feed bf16(e*s) into the out GEMM:  out[b,j,d] = sum_i attn[b,i,j]*v[b,i,d].
// Grid: b x 64 j-tiles(32) = 512 blocks. Wave w: jg=w&1 (16 j), dgrp=w>>1 (64 d).
// A = normalized attn^T tile (transposed into LDS bf16), B = vT tile from g_vT.
__global__ __launch_bounds__(256) void norm_out_kernel(float* __restrict__ attn,
                                                       float* __restrict__ out) {
    __shared__ short aT[32 * 72];   // [j_local][i_local], pitch 72
    __shared__ short vT[128 * 72];  // [d][i_local], pitch 72
    const int tid = threadIdx.x;
    const int b = blockIdx.x >> 6, j0 = (blockIdx.x & 63) * 32;
    const int w = tid >> 6, lid = tid & 63, n16 = lid & 15, quad = lid >> 4;
    const int jg = w & 1, dgrp = w >> 1;
    float* ab = attn + (size_t)b * L_ * L_;
    const unsigned short* vTb = g_vT + (size_t)b * D_ * L_;
    const float* lp0 = g_lpart + (size_t)b * L_;
    const float* lp1 = g_lpart + (size_t)B_ * L_ + (size_t)b * L_;

    f32x4 oacc[4];
    #pragma unroll
    for (int dc = 0; dc < 4; ++dc) oacc[dc] = (f32x4){0.f, 0.f, 0.f, 0.f};

    for (int i0 = 0; i0 < L_; i0 += 64) {
        __syncthreads();
        #pragma unroll
        for (int c = 0; c < 2; ++c) {  // attn tile [64 i][32 j]: normalize + store + transpose
            const int g = c * 256 + tid, il = g >> 3, jf = g & 7;
            const float s = 1.0f / (lp0[i0 + il] + lp1[i0 + il]);
            float* ap = ab + (size_t)(i0 + il) * L_ + j0 + jf * 4;
            float4 t = ld4(ap);
            t.x *= s; t.y *= s; t.z *= s; t.w *= s;
            *(float4*)ap = t;  // normalized attn output (in place)
            aT[(jf * 4 + 0) * 72 + il] = bf(t.x);
            aT[(jf * 4 + 1) * 72 + il] = bf(t.y);
            aT[(jf * 4 + 2) * 72 + il] = bf(t.z);
            aT[(jf * 4 + 3) * 72 + il] = bf(t.w);
        }
        #pragma unroll
        for (int c = 0; c < 4; ++c) {  // vT tile [128 d][64 i] (already bf16)
            const int g = c * 256 + tid, d = g >> 3, ic = (g & 7) * 8;
            *(short8*)(vT + d * 72 + ic) =
                *(const short8*)(const void*)(vTb + (size_t)d * L_ + i0 + ic);
        }
        __syncthreads();
        #pragma unroll
        for (int kc = 0; kc < 2; ++kc) {
            const short8 af = *(const short8*)(aT + (jg * 16 + n16) * 72 + kc * 32 + quad * 8);
            #pragma unroll
            for (int dc = 0; dc < 4; ++dc) {
                const short8 vf = *(const short8*)(
                    vT + (dgrp * 64 + dc * 16 + n16) * 72 + kc * 32 + quad * 8);
                oacc[dc] = mfma16(af, vf, oacc[dc]);
            }
        }
    }
    // D[row=j_local=quad*4+r][col=d=n16] per dc chunk
    #pragma unroll
    for (int dc = 0; dc < 4; ++dc)
        #pragma unroll
        for (int r = 0; r < 4; ++r)
            out[((size_t)b * L_ + j0 + jg * 16 + quad * 4 + r) * D_ + dgrp * 64 + dc * 16 + n16] =
                oacc[dc][r];
}

extern "C" void kernel_launch(void* const* d_in, const int* in_sizes, int n_in,
                              void* d_out, int out_size, void* d_ws, size_t ws_size,
                              hipStream_t stream) {
    const float* q = (const float*)d_in[0];
    // d_in[1] = k: unused by the reference (scores come from q and v).
    const float* v = (const float*)d_in[2];
    float* out  = (float*)d_out;
    float* attn = out + (size_t)B_ * L_ * D_;  // outputs concatenated: [out | attn]

    vT_kernel<<<dim3(B_ * 32), 256, 0, stream>>>(v);
    score_exp_kernel<<<dim3(B_ * 64), 256, 0, stream>>>(q, v, attn);
    norm_out_kernel<<<dim3(B_ * 64), 256, 0, stream>>>(attn, out);

    (void)in_sizes; (void)n_in; (void)out_size; (void)d_ws; (void)ws_size;
}